// Round 9
// baseline (244.214 us; speedup 1.0000x reference)
//
#include <hip/hip_runtime.h>
#include <cmath>

#define HW 256
#define NIMG 48
#define NCH 3
#define NPLANE (NIMG * NCH)
#define STRIP 29          // output rows per block; grid 144*9 = 1296 = 5.06/CU
#define NSTRIP 9          // targets 5 waves/SIMD band (VGPR<=51 at 256-pool)
#define NIN (STRIP + 10)  // 39 input rows per block
#define CHUNK 22          // even multiple of 11: i%11 and i%2 compile-time
#define NCHUNK 2          // 44 slots; guards prune past i=39
#define NSLOT 64          // ws accumulator slots
#define NBLK (NPLANE * NSTRIP)

typedef float f2 __attribute__((ext_vector_type(2)));
typedef float f4 __attribute__((ext_vector_type(4)));

// ws doubles: ws[0..63] partial sums; ws[64] holds the arrival counter (uint)
__global__ void zero_ws_kernel(double* ws) {
    if (threadIdx.x < NSLOT + 1) ws[threadIdx.x] = 0.0;
}

// ---------------------------------------------------------------------------
// Fused SSIM + L1 + weighted-L1, v-first + packed-f32 math (round 9).
//
// Round-8 ledger: dur = 46us VALU-busy + 32us idle across ALL structures.
// This round attacks both:
//  (1) v_pk_fma_f32: the (p,t) and (mux,muy)/(exx,eyy) pairs are computed
//      with float2 ext-vectors -> pk ops halve conv instruction count.
//      Per-element IEEE semantics identical (pk_fma = fma per half, same
//      accumulation order as the scalar version).
//  (2) VGPR=48 (r8) is in the 5-waves/SIMD band (256/48); grid raised to
//      1296 blocks = 5.06/CU to actually supply 5 waves (r8's 1008 = 3.94).
//  (3) final_kernel merged in via last-block pattern (arrival counter +
//      __threadfence release; atomic-RMW reads so cross-XCD visibility is
//      guaranteed) -> one fewer graph node.
// Structure otherwise = round 8 (proven): per-row raw s_barrier+lgkmcnt(0)
// (vmcnt NOT drained -> depth-2 prefetch survives), moment double-buffer by
// row parity. Round-1/4/5: no launch_bounds caps. Round-3: sbbs barrier.
// ---------------------------------------------------------------------------
__launch_bounds__(256)
__global__ void fused_kernel(const float* __restrict__ pred,
                             const float* __restrict__ target,
                             const float* __restrict__ lmk,
                             double* __restrict__ ws,
                             float* __restrict__ out)
{
    const int plane = blockIdx.x;          // n*3 + c
    const int n     = plane / 3;
    const int r0    = blockIdx.y * STRIP;
    const int x     = threadIdx.x;

    __shared__ f4     mva[2][HW + 10];     // v-moments: mux,muy,exx,eyy
    __shared__ float  mvb[2][HW + 10];     // v-moment: exy
    __shared__ float  sxc[STRIP][24];      // crossing x per (row, edge)
    __shared__ int    srowflag[STRIP];     // bit p: poly p valid && row in y-range
    __shared__ float  slm[48];             // landmarks 36..59 (x,y)
    __shared__ float  sbbs[12];            // per poly: xmin,xmax,ymin,ymax
    __shared__ float  svalids[3];
    __shared__ float  red[12];
    __shared__ int    sdone;

    // Gaussian weights, symmetric: keep only 6 (g[j] == g[10-j])
    float g6[6];
    {
        float gg[11]; float gs = 0.f;
#pragma unroll
        for (int q = 0; q < 11; ++q) {
            float c = (float)q - 5.0f;
            gg[q] = expf(-c * c / 4.5f);
            gs += gg[q];
        }
#pragma unroll
        for (int q = 0; q < 6; ++q) g6[q] = gg[q] / gs;
    }
#define GW(j) g6[(j) < 6 ? (j) : 10 - (j)]   // j always compile-time

    // ---- prologue ----------------------------------------------------------
    if (x < 48) slm[x] = lmk[n * 136 + 72 + x];
    if (x < 5) {
        const f4 z4 = {0.f, 0.f, 0.f, 0.f};
        mva[0][x] = z4; mva[0][261 + x] = z4;
        mva[1][x] = z4; mva[1][261 + x] = z4;
        mvb[0][x] = 0.f; mvb[0][261 + x] = 0.f;
        mvb[1][x] = 0.f; mvb[1][261 + x] = 0.f;
    }
    __syncthreads();   // slm ready

    if (x < 3) {
        const int s0 = (x == 0) ? 0 : (x == 1) ? 6 : 12;
        const int L  = (x == 2) ? 12 : 6;
        float xmn = 3e38f, xmx = -3e38f, ymn = 3e38f, ymx = -3e38f;
        for (int q = 0; q < L; ++q) {
            float px = slm[2 * (s0 + q)], py = slm[2 * (s0 + q) + 1];
            xmn = fminf(xmn, px); xmx = fmaxf(xmx, px);
            ymn = fminf(ymn, py); ymx = fmaxf(ymx, py);
        }
        xmn = floorf(xmn); xmx = floorf(xmx); ymn = floorf(ymn); ymx = floorf(ymx);
        sbbs[4 * x + 0] = xmn; sbbs[4 * x + 1] = xmx;
        sbbs[4 * x + 2] = ymn; sbbs[4 * x + 3] = ymx;
        svalids[x] = (xmn >= 0.f && ymn >= 0.f && xmx < 256.f && ymx < 256.f) ? 1.f : 0.f;
    }

#pragma unroll
    for (int u = 0; u < (STRIP * 24 + 255) / 256; ++u) {
        int idx = x + 256 * u;
        if (idx < STRIP * 24) {
            int r = idx / 24, e = idx - r * 24;
            float Y = (float)(r0 + r);
            const int s0 = (e < 6) ? 0 : (e < 12) ? 6 : 12;
            const int L  = (e < 12) ? 6 : 12;
            int il = e - s0;
            int i2 = (il + 1 == L) ? 0 : il + 1;
            float x1 = slm[2 * (s0 + il)], y1 = slm[2 * (s0 + il) + 1];
            float x2 = slm[2 * (s0 + i2)], y2 = slm[2 * (s0 + i2) + 1];
            bool crossing = (y1 > Y) != (y2 > Y);
            // exact reference fp32 expression order
            float xc = (x2 - x1) * (Y - y1) / (y2 - y1 + 1e-6f) + x1;
            sxc[r][e] = crossing ? xc : -3e38f;
        }
    }
    __syncthreads();   // sbbs/svalids visible to all (round-3 fix); sxc ready

    if (x < STRIP) {
        float Y = (float)(r0 + x);
        int f = 0;
        if (svalids[0] != 0.f && Y >= sbbs[2]  && Y < sbbs[3])  f |= 1;
        if (svalids[1] != 0.f && Y >= sbbs[6]  && Y < sbbs[7])  f |= 2;
        if (svalids[2] != 0.f && Y >= sbbs[10] && Y < sbbs[11]) f |= 4;
        srowflag[x] = f;
    }
    __syncthreads();   // srowflag ready; pads ready

    // column-x base pointers (coalesced across threads)
    const float* __restrict__ pp = pred   + (size_t)plane * (HW * HW) + x;
    const float* __restrict__ tp = target + (size_t)plane * (HW * HW) + x;

    // raw-row register ring (11 x float2 = 22 VGPR) + depth-2 prefetch pair
    f2 ring[11];
    f2 pfa, pfb;
    {   // warmup: rows i=0 (r0-5) and i=1 (r0-4)
        int ra = r0 - 5;
        bool va = (ra >= 0);
        pfa.x = va ? pp[(size_t)ra * HW] : 0.f;
        pfa.y = va ? tp[(size_t)ra * HW] : 0.f;
        int rb = r0 - 4;
        bool vb = (rb >= 0);
        pfb.x = vb ? pp[(size_t)rb * HW] : 0.f;
        pfb.y = vb ? tp[(size_t)rb * HW] : 0.f;
    }

    float acc = 0.f, accl1 = 0.f, acclw = 0.f;
    const float X = (float)x;

    for (int c = 0; c < NCHUNK; ++c) {
#pragma unroll
        for (int t = 0; t < CHUNK; ++t) {
            const int i  = CHUNK * c + t;   // runtime (c), t compile-time
            const int sr = t % 11;          // ring slot of row i (22c % 11 == 0)

            if (i < NIN) {
                // consume prefetch (issued 2 iters ago) into the ring
                if ((t & 1) == 0) ring[sr] = pfa;
                else              ring[sr] = pfb;
                // issue load for row i+2 (consumed 2 iters later)
                {
                    int rin2 = r0 - 3 + i;
                    bool v = (i + 2 < NIN) && (rin2 >= 0) && (rin2 < HW);
                    f2 l = {0.f, 0.f};
                    if (v) {
                        l.x = pp[(size_t)rin2 * HW];
                        l.y = tp[(size_t)rin2 * HW];
                    }
                    if ((t & 1) == 0) pfa = l;
                    else              pfb = l;
                }

                // ---- L1 + weighted L1 for raw row r_in = r0-5+i ------------
                if (i >= 5 && i < 5 + STRIP) {      // runtime uniform
                    int r_in = r0 - 5 + i;
                    if (r_in < HW) {
                        f2 pr = ring[sr];
                        float ad = fabsf(pr.x - pr.y);
                        accl1 += ad;
                        float wgt = 1.f;
                        const int flags = srowflag[i - 5];   // broadcast read
                        if (flags) {                 // wave-uniform branch
                            const float* xc = sxc[i - 5];
                            int c0 = 0, c1 = 0, c2 = 0;
#pragma unroll
                            for (int e = 0; e < 6; ++e)   c0 += (X < xc[e]) ? 1 : 0;
#pragma unroll
                            for (int e = 6; e < 12; ++e)  c1 += (X < xc[e]) ? 1 : 0;
#pragma unroll
                            for (int e = 12; e < 24; ++e) c2 += (X < xc[e]) ? 1 : 0;
                            if ((flags & 1) && (c0 & 1) && X >= sbbs[0] && X < sbbs[1]) wgt += 3.f;
                            if ((flags & 2) && (c1 & 1) && X >= sbbs[4] && X < sbbs[5]) wgt += 3.f;
                            if ((flags & 4) && (c2 & 1) && X >= sbbs[8] && X < sbbs[9]) wgt += 2.f;
                        }
                        acclw += wgt * ad;
                    }
                }
            }

            // ---- vertical conv (packed) -> moment row r = r0 + i - 10 ------
            if (i >= 10 && i < 10 + STRIP) {        // runtime uniform
                int r = r0 + i - 10;
                if (r < HW) {
                    f2 mu = {0.f, 0.f};             // (mux, muy)
                    f2 sq = {0.f, 0.f};             // (exx, eyy)
                    float exy = 0.f;
#pragma unroll
                    for (int j = 0; j < 11; ++j) {
                        const int s = (t + 1 + j) % 11;   // compile-time
                        float w = GW(j);
                        f2 v  = ring[s];
                        f2 wv = w * v;                        // pk_mul: (wp,wt)
                        mu += wv;                             // pk_add
                        sq = __builtin_elementwise_fma(wv, v, sq);  // pk_fma
                        exy = fmaf(wv.x, v.y, exy);           // scalar fma
                    }
                    f4 o; o.x = mu.x; o.y = mu.y; o.z = sq.x; o.w = sq.y;
                    mva[t & 1][x + 5] = o;
                    mvb[t & 1][x + 5] = exy;        // parity (i-10)&1 == t&1
                }
            }

            // ---- horizontal conv (packed) + SSIM, row r' = r0 + i - 11 -----
            if (i >= 11 && i < 11 + STRIP) {        // runtime uniform
                int rr = r0 + i - 11;
                if (rr < HW) {
                    const int b = (t + 1) & 1;      // (i-11)&1, compile-time
                    f2 M = {0.f, 0.f};              // (Mx, My)
                    f2 E = {0.f, 0.f};              // (Exx, Eyy)
                    float Exy = 0.f;
#pragma unroll
                    for (int k = 0; k < 11; ++k) {
                        float w = GW(k);
                        f2 w2 = {w, w};
                        f4 m4 = mva[b][x + k];
                        f2 lo = {m4.x, m4.y};
                        f2 hi = {m4.z, m4.w};
                        float m1 = mvb[b][x + k];
                        M = __builtin_elementwise_fma(w2, lo, M);
                        E = __builtin_elementwise_fma(w2, hi, E);
                        Exy = fmaf(w, m1, Exy);
                    }
                    float sx  = E.x - M.x * M.x;
                    float sy  = E.y - M.y * M.y;
                    float sxy = Exy - M.x * M.y;
                    const float C1 = 1e-4f, C2 = 9e-4f;
                    float num = (2.f * M.x * M.y + C1) * (2.f * sxy + C2);
                    float den = (M.x * M.x + M.y * M.y + C1) * (sx + sy + C2);
                    acc += 0.5f * (1.f - num / (den + 1e-8f));
                }
            }

            // raw barrier: drain LDS (moment writes visible) but NOT vmcnt,
            // so depth-2 prefetch loads stay in flight across it.
            asm volatile("s_waitcnt lgkmcnt(0)" ::: "memory");
            __builtin_amdgcn_s_barrier();
        }
    }

    // ---- block reduction ---------------------------------------------------
#pragma unroll
    for (int off = 32; off > 0; off >>= 1) {
        acc   += __shfl_down(acc, off, 64);
        accl1 += __shfl_down(accl1, off, 64);
        acclw += __shfl_down(acclw, off, 64);
    }
    if ((x & 63) == 0) {
        int w = x >> 6;
        red[w] = acc; red[4 + w] = accl1; red[8 + w] = acclw;
    }
    __syncthreads();
    if (x == 0) {
        double s = 10.0 * ((double)red[0] + red[1] + red[2]  + red[3])
                 + 10.0 * ((double)red[4] + red[5] + red[6]  + red[7])
                 +  5.0 * ((double)red[8] + red[9] + red[10] + red[11]);
        atomicAdd(&ws[(blockIdx.y * NPLANE + blockIdx.x) & (NSLOT - 1)], s);
    }

    // ---- last-block finalize (replaces final_kernel) -----------------------
    __threadfence();   // release: our ws add visible before counter bump
    if (x == 0) {
        unsigned int old = atomicAdd((unsigned int*)(ws + NSLOT), 1u);
        sdone = (old == (unsigned int)(NBLK - 1)) ? 1 : 0;
    }
    __syncthreads();
    if (sdone) {
        // atomic-RMW reads: guaranteed to see device-scope atomics from all
        // XCDs (plain loads could be served stale by a local cache).
        double v = (x < NSLOT) ? atomicAdd(&ws[x], 0.0) : 0.0;
        if (x < 64) {
#pragma unroll
            for (int off = 32; off > 0; off >>= 1)
                v += __shfl_down(v, off, 64);
            if (x == 0) {
                const double denom = (double)NIMG * NCH * HW * HW;
                out[0] = (float)(v / denom);
            }
        }
    }
}

// ---------------------------------------------------------------------------
extern "C" void kernel_launch(void* const* d_in, const int* in_sizes, int n_in,
                              void* d_out, int out_size, void* d_ws, size_t ws_size,
                              hipStream_t stream)
{
    const float* pred   = (const float*)d_in[0];
    const float* target = (const float*)d_in[1];
    const float* lmk    = (const float*)d_in[2];
    float* out  = (float*)d_out;
    double* ws  = (double*)d_ws;

    hipLaunchKernelGGL(zero_ws_kernel, dim3(1), dim3(128), 0, stream, ws);
    hipLaunchKernelGGL(fused_kernel, dim3(NPLANE, NSTRIP), dim3(256), 0, stream,
                       pred, target, lmk, ws, out);
}

// Round 11
// 179.505 us; speedup vs baseline: 1.3605x; 1.3605x over previous
//
#include <hip/hip_runtime.h>
#include <cmath>

#define HW 256
#define NIMG 48
#define NCH 3
#define NPLANE (NIMG * NCH)
#define STRIP 37          // output rows per block; grid 144*7 = 1008 <= 1024
#define NSTRIP 7          // one residency round at ~4 blocks/CU
#define NIN (STRIP + 10)  // 47 input rows per block
#define NCHUNK 3          // 3 chunks x 11 phases; phases >= PHASES skipped
#define PHASES 25         // covers rows 0..49 (> NIN) + h-conv epilogue
#define NSLOT 64          // ws accumulator slots

// ws doubles: ws[0..63] partial sums of (10*d + 10*l1 + 5*lw)
__global__ void zero_ws_kernel(double* ws) {
    if (threadIdx.x < NSLOT) ws[threadIdx.x] = 0.0;
}

// ---------------------------------------------------------------------------
// Fused SSIM + L1 + weighted-L1, v-first, 2-ROWS-PER-BARRIER-PHASE (round 11
// = round 10 with the warmup OOB-load fixed).
//
// r10 crash: `pfbp = pp[(size_t)(r0-4)*HW]` issued UNCONDITIONALLY; r0=0 ->
// negative row -> size_t wrap -> wild load -> GPU fault. Fix: guarded
// ternary (control-dependent load), as in verified r8.
//
// r8 ledger: per-iter wall 2856 cy = 1708 busy + ~1150 per-barrier fixed
// stall (barrier convergence + LDS round trip + lgkm drain). Stall is
// per-PHASE -> 2 rows per phase: 66 -> 25 barriers.
// r9 lessons REVERTED: pk/f2 math (scalarized), grid 1296 (stall explosion),
// merged finalize (harness overhead fixed ~74us regardless of kernel count).
// Structure = r8 otherwise: thread x owns column x; v-conv on a 22-reg raw
// ring; 5 moments through LDS (float4+float, conflict-free); depth-2
// register prefetch survives barriers (lgkmcnt(0)-only drain, vmcnt NOT
// drained). Moment buffers [2 dbuf][2 rows]; write buf g&1, read (g-1)&1.
// Dead phases (g>=PHASES) skip the barrier via UNIFORM continue.
// r1/r4/r5: no launch_bounds caps. r3: barrier after sbbs writes.
// ---------------------------------------------------------------------------
__launch_bounds__(256)
__global__ void fused_kernel(const float* __restrict__ pred,
                             const float* __restrict__ target,
                             const float* __restrict__ lmk,
                             double* __restrict__ ws)
{
    const int plane = blockIdx.x;          // n*3 + c
    const int n     = plane / 3;
    const int r0    = blockIdx.y * STRIP;
    const int x     = threadIdx.x;

    __shared__ float4 mva[2][2][HW + 10];  // [dbuf][row] mux,muy,exx,eyy
    __shared__ float  mvb[2][2][HW + 10];  // [dbuf][row] exy
    __shared__ float  sxc[STRIP][24];      // crossing x per (row, edge)
    __shared__ int    srowflag[STRIP];     // bit p: poly p valid && row in y-range
    __shared__ float  slm[48];             // landmarks 36..59 (x,y)
    __shared__ float  sbbs[12];            // per poly: xmin,xmax,ymin,ymax
    __shared__ float  svalids[3];
    __shared__ float  red[12];

    // Gaussian weights, symmetric: keep only 6 (g[j] == g[10-j])
    float g6[6];
    {
        float gg[11]; float gs = 0.f;
#pragma unroll
        for (int q = 0; q < 11; ++q) {
            float c = (float)q - 5.0f;
            gg[q] = expf(-c * c / 4.5f);
            gs += gg[q];
        }
#pragma unroll
        for (int q = 0; q < 6; ++q) g6[q] = gg[q] / gs;
    }
#define GW(j) g6[(j) < 6 ? (j) : 10 - (j)]   // j always compile-time

    // ---- prologue ----------------------------------------------------------
    if (x < 48) slm[x] = lmk[n * 136 + 72 + x];
    if (x < 5) {
        const float4 z4 = make_float4(0.f, 0.f, 0.f, 0.f);
#pragma unroll
        for (int b = 0; b < 2; ++b)
#pragma unroll
            for (int q = 0; q < 2; ++q) {
                mva[b][q][x] = z4; mva[b][q][261 + x] = z4;
                mvb[b][q][x] = 0.f; mvb[b][q][261 + x] = 0.f;
            }
    }
    __syncthreads();   // slm ready

    if (x < 3) {
        const int s0 = (x == 0) ? 0 : (x == 1) ? 6 : 12;
        const int L  = (x == 2) ? 12 : 6;
        float xmn = 3e38f, xmx = -3e38f, ymn = 3e38f, ymx = -3e38f;
        for (int q = 0; q < L; ++q) {
            float px = slm[2 * (s0 + q)], py = slm[2 * (s0 + q) + 1];
            xmn = fminf(xmn, px); xmx = fmaxf(xmx, px);
            ymn = fminf(ymn, py); ymx = fmaxf(ymx, py);
        }
        xmn = floorf(xmn); xmx = floorf(xmx); ymn = floorf(ymn); ymx = floorf(ymx);
        sbbs[4 * x + 0] = xmn; sbbs[4 * x + 1] = xmx;
        sbbs[4 * x + 2] = ymn; sbbs[4 * x + 3] = ymx;
        svalids[x] = (xmn >= 0.f && ymn >= 0.f && xmx < 256.f && ymx < 256.f) ? 1.f : 0.f;
    }

#pragma unroll
    for (int u = 0; u < (STRIP * 24 + 255) / 256; ++u) {
        int idx = x + 256 * u;
        if (idx < STRIP * 24) {
            int r = idx / 24, e = idx - r * 24;
            float Y = (float)(r0 + r);
            const int s0 = (e < 6) ? 0 : (e < 12) ? 6 : 12;
            const int L  = (e < 12) ? 6 : 12;
            int il = e - s0;
            int i2 = (il + 1 == L) ? 0 : il + 1;
            float x1 = slm[2 * (s0 + il)], y1 = slm[2 * (s0 + il) + 1];
            float x2 = slm[2 * (s0 + i2)], y2 = slm[2 * (s0 + i2) + 1];
            bool crossing = (y1 > Y) != (y2 > Y);
            // exact reference fp32 expression order
            float xc = (x2 - x1) * (Y - y1) / (y2 - y1 + 1e-6f) + x1;
            sxc[r][e] = crossing ? xc : -3e38f;
        }
    }
    __syncthreads();   // sbbs/svalids visible to all (round-3 fix); sxc ready

    if (x < STRIP) {
        float Y = (float)(r0 + x);
        int f = 0;
        if (svalids[0] != 0.f && Y >= sbbs[2]  && Y < sbbs[3])  f |= 1;
        if (svalids[1] != 0.f && Y >= sbbs[6]  && Y < sbbs[7])  f |= 2;
        if (svalids[2] != 0.f && Y >= sbbs[10] && Y < sbbs[11]) f |= 4;
        srowflag[x] = f;
    }
    __syncthreads();   // srowflag + pads ready

    // column-x base pointers (coalesced across threads)
    const float* __restrict__ pp = pred   + (size_t)plane * (HW * HW) + x;
    const float* __restrict__ tp = target + (size_t)plane * (HW * HW) + x;

    // raw-row register ring (22 VGPR) + depth-2 prefetch pair
    float rp[11], rt[11];
    float pfap, pfat, pfbp, pfbt;
    {   // warmup: rows i=0 (r0-5) and i=1 (r0-4); GUARDED loads (r10 fix)
        int ra = r0 - 5;
        bool va = (ra >= 0);
        pfap = va ? pp[(size_t)ra * HW] : 0.f;
        pfat = va ? tp[(size_t)ra * HW] : 0.f;
        int rb = r0 - 4;
        bool vb = (rb >= 0);
        pfbp = vb ? pp[(size_t)rb * HW] : 0.f;
        pfbt = vb ? tp[(size_t)rb * HW] : 0.f;
    }

    float acc = 0.f, accl1 = 0.f, acclw = 0.f;
    const float X = (float)x;

    // phases g = 11*c + u; rows i0 = 2g, i1 = 2g+1 enter per phase
    for (int c = 0; c < NCHUNK; ++c) {
#pragma unroll
        for (int u = 0; u < 11; ++u) {
            const int g  = 11 * c + u;     // phase index (uniform runtime)
            if (g >= PHASES) continue;     // uniform: dead phases skip barrier too
            const int i0 = 2 * g;          // first row entering this phase
            const int wb = g & 1;          // write buffer (uniform runtime)
            const int rbuf = wb ^ 1;       // read buffer (prev phase's writes)
            // ring slots: i0 % 11 == (2u) % 11 (22c % 11 == 0), compile-time
            const int s0 = (2 * u) % 11;
            const int s1 = (2 * u + 1) % 11;

            // ---- consume prefetch + issue next + L1, rows i0 (pfa), i1 (pfb)
#pragma unroll
            for (int q = 0; q < 2; ++q) {
                const int i  = i0 + q;
                const int sr = q ? s1 : s0;
                if (i < NIN) {
                    if (q == 0) { rp[sr] = pfap; rt[sr] = pfat; }
                    else        { rp[sr] = pfbp; rt[sr] = pfbt; }
                    {   // issue load for row i+2 (consumed next phase)
                        int rin2 = r0 - 3 + i;
                        bool v = (i + 2 < NIN) && (rin2 >= 0) && (rin2 < HW);
                        float lp = 0.f, lt = 0.f;
                        if (v) {
                            lp = pp[(size_t)rin2 * HW];
                            lt = tp[(size_t)rin2 * HW];
                        }
                        if (q == 0) { pfap = lp; pfat = lt; }
                        else        { pfbp = lp; pfbt = lt; }
                    }
                    // L1 + weighted L1 for raw row r_in = r0-5+i
                    if (i >= 5 && i < 5 + STRIP) {
                        int r_in = r0 - 5 + i;
                        if (r_in < HW) {
                            float ad = fabsf(rp[sr] - rt[sr]);
                            accl1 += ad;
                            float wgt = 1.f;
                            const int flags = srowflag[i - 5];
                            if (flags) {             // wave-uniform branch
                                const float* xc = sxc[i - 5];
                                int c0 = 0, c1 = 0, c2 = 0;
#pragma unroll
                                for (int e = 0; e < 6; ++e)   c0 += (X < xc[e]) ? 1 : 0;
#pragma unroll
                                for (int e = 6; e < 12; ++e)  c1 += (X < xc[e]) ? 1 : 0;
#pragma unroll
                                for (int e = 12; e < 24; ++e) c2 += (X < xc[e]) ? 1 : 0;
                                if ((flags & 1) && (c0 & 1) && X >= sbbs[0] && X < sbbs[1]) wgt += 3.f;
                                if ((flags & 2) && (c1 & 1) && X >= sbbs[4] && X < sbbs[5]) wgt += 3.f;
                                if ((flags & 4) && (c2 & 1) && X >= sbbs[8] && X < sbbs[9]) wgt += 2.f;
                            }
                            acclw += wgt * ad;
                        }
                    }
                }
            }

            // ---- v-conv rows i0,i1 -> moment rows (write buf wb, slots 0/1)
#pragma unroll
            for (int q = 0; q < 2; ++q) {
                const int i = i0 + q;
                if (i >= 10 && i < 10 + STRIP) {
                    int r = r0 + i - 10;
                    if (r < HW) {
                        float mux = 0.f, muy = 0.f, exx = 0.f, eyy = 0.f, exy = 0.f;
#pragma unroll
                        for (int j = 0; j < 11; ++j) {
                            const int s = (2 * u + q + 1 + j) % 11;  // compile-time
                            float w = GW(j);
                            float p = rp[s], t = rt[s];
                            float wp = w * p, wt = w * t;
                            mux += wp; muy += wt;
                            exx = fmaf(wp, p, exx);
                            eyy = fmaf(wt, t, eyy);
                            exy = fmaf(wp, t, exy);
                        }
                        mva[wb][q][x + 5] = make_float4(mux, muy, exx, eyy);
                        mvb[wb][q][x + 5] = exy;
                    }
                }
            }

            // ---- h-conv + SSIM: prev phase's moment rows (buf rbuf) --------
            // rows r' = r0 + i0 - 12 (slot 0) and r0 + i0 - 11 (slot 1)
#pragma unroll
            for (int q = 0; q < 2; ++q) {
                const int hr = i0 - 12 + q;         // row offset within strip
                if (i0 >= 12 - q && hr < STRIP) {
                    int rr = r0 + hr;
                    if (rr < HW) {
                        float Mx = 0.f, My = 0.f, Exx = 0.f, Eyy = 0.f, Exy = 0.f;
#pragma unroll
                        for (int k = 0; k < 11; ++k) {
                            float w = GW(k);
                            float4 m4 = mva[rbuf][q][x + k];
                            float  m1 = mvb[rbuf][q][x + k];
                            Mx  = fmaf(w, m4.x, Mx);
                            My  = fmaf(w, m4.y, My);
                            Exx = fmaf(w, m4.z, Exx);
                            Eyy = fmaf(w, m4.w, Eyy);
                            Exy = fmaf(w, m1,  Exy);
                        }
                        float sx  = Exx - Mx * Mx;
                        float sy  = Eyy - My * My;
                        float sxy = Exy - Mx * My;
                        const float C1 = 1e-4f, C2 = 9e-4f;
                        float num = (2.f * Mx * My + C1) * (2.f * sxy + C2);
                        float den = (Mx * Mx + My * My + C1) * (sx + sy + C2);
                        acc += 0.5f * (1.f - num / (den + 1e-8f));
                    }
                }
            }

            // one barrier per PHASE: drain LDS (writes+reads) but NOT vmcnt,
            // so the register prefetch loads stay in flight across it.
            asm volatile("s_waitcnt lgkmcnt(0)" ::: "memory");
            __builtin_amdgcn_s_barrier();
        }
    }

    // ---- block reduction ---------------------------------------------------
#pragma unroll
    for (int off = 32; off > 0; off >>= 1) {
        acc   += __shfl_down(acc, off, 64);
        accl1 += __shfl_down(accl1, off, 64);
        acclw += __shfl_down(acclw, off, 64);
    }
    if ((x & 63) == 0) {
        int w = x >> 6;
        red[w] = acc; red[4 + w] = accl1; red[8 + w] = acclw;
    }
    __syncthreads();
    if (x == 0) {
        double s = 10.0 * ((double)red[0] + red[1] + red[2]  + red[3])
                 + 10.0 * ((double)red[4] + red[5] + red[6]  + red[7])
                 +  5.0 * ((double)red[8] + red[9] + red[10] + red[11]);
        atomicAdd(&ws[(blockIdx.y * NPLANE + blockIdx.x) & (NSLOT - 1)], s);
    }
}

// ---------------------------------------------------------------------------
__global__ void final_kernel(const double* __restrict__ ws, float* __restrict__ out) {
    double v = ws[threadIdx.x];
#pragma unroll
    for (int off = 32; off > 0; off >>= 1)
        v += __shfl_down(v, off, 64);
    if (threadIdx.x == 0) {
        const double denom = (double)NIMG * NCH * HW * HW;
        out[0] = (float)(v / denom);
    }
}

// ---------------------------------------------------------------------------
extern "C" void kernel_launch(void* const* d_in, const int* in_sizes, int n_in,
                              void* d_out, int out_size, void* d_ws, size_t ws_size,
                              hipStream_t stream)
{
    const float* pred   = (const float*)d_in[0];
    const float* target = (const float*)d_in[1];
    const float* lmk    = (const float*)d_in[2];
    float* out  = (float*)d_out;
    double* ws  = (double*)d_ws;

    hipLaunchKernelGGL(zero_ws_kernel, dim3(1), dim3(64), 0, stream, ws);
    hipLaunchKernelGGL(fused_kernel, dim3(NPLANE, NSTRIP), dim3(256), 0, stream,
                       pred, target, lmk, ws);
    hipLaunchKernelGGL(final_kernel, dim3(1), dim3(64), 0, stream, ws, out);
}

// Round 12
// 155.554 us; speedup vs baseline: 1.5700x; 1.1540x over previous
//
#include <hip/hip_runtime.h>
#include <cmath>

#define HW 256
#define NIMG 48
#define NCH 3
#define NPLANE (NIMG * NCH)
#define STRIP 29          // output rows per block; grid 144*9 = 1296 = 5.06/CU
#define NSTRIP 9          // supplies the 5th wave/SIMD slot (VGPR 48 -> cap 5)
#define NIN (STRIP + 10)  // 39 input rows per block
#define CHUNK 22          // even multiple of 11: i%11 and i%2 compile-time
#define NCHUNK 2          // 44 slots; guards prune past i=38
#define NSLOT 64          // ws accumulator slots

// ws doubles: ws[0..63] partial sums of (10*d + 10*l1 + 5*lw)
__global__ void zero_ws_kernel(double* ws) {
    if (threadIdx.x < NSLOT) ws[threadIdx.x] = 0.0;
}

// ---------------------------------------------------------------------------
// Fused SSIM + L1 + weighted-L1, v-first (round 12 = round 8 VERBATIM with
// grid 1008 -> 1296 only).
//
// Occupancy model (r0/r1/r2/r4/r6/r11): waves/SIMD = min(8, 256/VGPR).
// r8: VGPR=48 -> 5 waves/SIMD ALLOWED, but grid 1008 = 3.94 blk/CU supplied
// only 4. This round: STRIP 29 x NSTRIP 9 = 1296 blocks = 5.06/CU -> 5
// waves/SIMD supplied, 16-block tail. Pure A/B on TLP; everything else is
// the verified r8 code (78.5us fused, VALUBusy 59%).
// r9's 1296-grid regression was confounded (pk-math scalarization + per-
// block __threadfence); this isolates the grid variable.
// r11 lesson: 2-row phases cost VGPR 48->92 -> 2 waves/SIMD; abandoned.
// r1/r4/r5: no launch_bounds VGPR caps (they spill). r3: sbbs barrier.
// r10: warmup loads MUST be guarded ternaries (OOB size_t wrap -> fault).
// ---------------------------------------------------------------------------
__launch_bounds__(256)
__global__ void fused_kernel(const float* __restrict__ pred,
                             const float* __restrict__ target,
                             const float* __restrict__ lmk,
                             double* __restrict__ ws)
{
    const int plane = blockIdx.x;          // n*3 + c
    const int n     = plane / 3;
    const int r0    = blockIdx.y * STRIP;
    const int x     = threadIdx.x;

    __shared__ float4 mva[2][HW + 10];     // v-moments: mux,muy,exx,eyy
    __shared__ float  mvb[2][HW + 10];     // v-moment: exy
    __shared__ float  sxc[STRIP][24];      // crossing x per (row, edge)
    __shared__ int    srowflag[STRIP];     // bit p: poly p valid && row in y-range
    __shared__ float  slm[48];             // landmarks 36..59 (x,y)
    __shared__ float  sbbs[12];            // per poly: xmin,xmax,ymin,ymax
    __shared__ float  svalids[3];
    __shared__ float  red[12];

    // Gaussian weights, symmetric: keep only 6 (g[j] == g[10-j])
    float g6[6];
    {
        float gg[11]; float gs = 0.f;
#pragma unroll
        for (int q = 0; q < 11; ++q) {
            float c = (float)q - 5.0f;
            gg[q] = expf(-c * c / 4.5f);
            gs += gg[q];
        }
#pragma unroll
        for (int q = 0; q < 6; ++q) g6[q] = gg[q] / gs;
    }
#define GW(j) g6[(j) < 6 ? (j) : 10 - (j)]   // j always compile-time

    // ---- prologue ----------------------------------------------------------
    if (x < 48) slm[x] = lmk[n * 136 + 72 + x];
    if (x < 5) {
        const float4 z4 = make_float4(0.f, 0.f, 0.f, 0.f);
        mva[0][x] = z4; mva[0][261 + x] = z4;
        mva[1][x] = z4; mva[1][261 + x] = z4;
        mvb[0][x] = 0.f; mvb[0][261 + x] = 0.f;
        mvb[1][x] = 0.f; mvb[1][261 + x] = 0.f;
    }
    __syncthreads();   // slm ready

    if (x < 3) {
        const int s0 = (x == 0) ? 0 : (x == 1) ? 6 : 12;
        const int L  = (x == 2) ? 12 : 6;
        float xmn = 3e38f, xmx = -3e38f, ymn = 3e38f, ymx = -3e38f;
        for (int q = 0; q < L; ++q) {
            float px = slm[2 * (s0 + q)], py = slm[2 * (s0 + q) + 1];
            xmn = fminf(xmn, px); xmx = fmaxf(xmx, px);
            ymn = fminf(ymn, py); ymx = fmaxf(ymx, py);
        }
        xmn = floorf(xmn); xmx = floorf(xmx); ymn = floorf(ymn); ymx = floorf(ymx);
        sbbs[4 * x + 0] = xmn; sbbs[4 * x + 1] = xmx;
        sbbs[4 * x + 2] = ymn; sbbs[4 * x + 3] = ymx;
        svalids[x] = (xmn >= 0.f && ymn >= 0.f && xmx < 256.f && ymx < 256.f) ? 1.f : 0.f;
    }

#pragma unroll
    for (int u = 0; u < (STRIP * 24 + 255) / 256; ++u) {
        int idx = x + 256 * u;
        if (idx < STRIP * 24) {
            int r = idx / 24, e = idx - r * 24;
            float Y = (float)(r0 + r);
            const int s0 = (e < 6) ? 0 : (e < 12) ? 6 : 12;
            const int L  = (e < 12) ? 6 : 12;
            int il = e - s0;
            int i2 = (il + 1 == L) ? 0 : il + 1;
            float x1 = slm[2 * (s0 + il)], y1 = slm[2 * (s0 + il) + 1];
            float x2 = slm[2 * (s0 + i2)], y2 = slm[2 * (s0 + i2) + 1];
            bool crossing = (y1 > Y) != (y2 > Y);
            // exact reference fp32 expression order
            float xc = (x2 - x1) * (Y - y1) / (y2 - y1 + 1e-6f) + x1;
            sxc[r][e] = crossing ? xc : -3e38f;
        }
    }
    __syncthreads();   // sbbs/svalids visible to all (round-3 fix); sxc ready

    if (x < STRIP) {
        float Y = (float)(r0 + x);
        int f = 0;
        if (svalids[0] != 0.f && Y >= sbbs[2]  && Y < sbbs[3])  f |= 1;
        if (svalids[1] != 0.f && Y >= sbbs[6]  && Y < sbbs[7])  f |= 2;
        if (svalids[2] != 0.f && Y >= sbbs[10] && Y < sbbs[11]) f |= 4;
        srowflag[x] = f;
    }
    __syncthreads();   // srowflag ready; pads ready

    // column-x base pointers (coalesced across threads)
    const float* __restrict__ pp = pred   + (size_t)plane * (HW * HW) + x;
    const float* __restrict__ tp = target + (size_t)plane * (HW * HW) + x;

    // raw-row register ring (22 VGPR) + depth-2 prefetch pair
    float rp[11], rt[11];
    float pfap, pfat, pfbp, pfbt;
    {   // warmup: rows i=0 (r0-5) and i=1 (r0-4); GUARDED ternaries (r10 fix)
        int ra = r0 - 5;
        bool va = (ra >= 0);
        pfap = va ? pp[(size_t)ra * HW] : 0.f;
        pfat = va ? tp[(size_t)ra * HW] : 0.f;
        int rb = r0 - 4;
        bool vb = (rb >= 0);
        pfbp = vb ? pp[(size_t)rb * HW] : 0.f;
        pfbt = vb ? tp[(size_t)rb * HW] : 0.f;
    }

    float acc = 0.f, accl1 = 0.f, acclw = 0.f;
    const float X = (float)x;

    for (int c = 0; c < NCHUNK; ++c) {
#pragma unroll
        for (int t = 0; t < CHUNK; ++t) {
            const int i  = CHUNK * c + t;   // runtime (c), t compile-time
            const int sr = t % 11;          // ring slot of row i (22c % 11 == 0)

            if (i < NIN) {
                // consume prefetch (issued 2 iters ago) into the ring
                if ((t & 1) == 0) { rp[sr] = pfap; rt[sr] = pfat; }
                else              { rp[sr] = pfbp; rt[sr] = pfbt; }
                // issue load for row i+2 (waited at use, 2 iters later)
                {
                    int rin2 = r0 - 3 + i;
                    bool v = (i + 2 < NIN) && (rin2 >= 0) && (rin2 < HW);
                    float lp = 0.f, lt = 0.f;
                    if (v) {
                        lp = pp[(size_t)rin2 * HW];
                        lt = tp[(size_t)rin2 * HW];
                    }
                    if ((t & 1) == 0) { pfap = lp; pfat = lt; }
                    else              { pfbp = lp; pfbt = lt; }
                }

                // ---- L1 + weighted L1 for raw row r_in = r0-5+i ------------
                if (i >= 5 && i < 5 + STRIP) {      // runtime uniform
                    int r_in = r0 - 5 + i;
                    if (r_in < HW) {
                        float ad = fabsf(rp[sr] - rt[sr]);
                        accl1 += ad;
                        float wgt = 1.f;
                        const int flags = srowflag[i - 5];   // broadcast read
                        if (flags) {                 // wave-uniform branch
                            const float* xc = sxc[i - 5];
                            int c0 = 0, c1 = 0, c2 = 0;
#pragma unroll
                            for (int e = 0; e < 6; ++e)   c0 += (X < xc[e]) ? 1 : 0;
#pragma unroll
                            for (int e = 6; e < 12; ++e)  c1 += (X < xc[e]) ? 1 : 0;
#pragma unroll
                            for (int e = 12; e < 24; ++e) c2 += (X < xc[e]) ? 1 : 0;
                            if ((flags & 1) && (c0 & 1) && X >= sbbs[0] && X < sbbs[1]) wgt += 3.f;
                            if ((flags & 2) && (c1 & 1) && X >= sbbs[4] && X < sbbs[5]) wgt += 3.f;
                            if ((flags & 4) && (c2 & 1) && X >= sbbs[8] && X < sbbs[9]) wgt += 2.f;
                        }
                        acclw += wgt * ad;
                    }
                }
            }

            // ---- vertical conv -> moment row r = r0 + i - 10 ---------------
            if (i >= 10 && i < 10 + STRIP) {        // runtime uniform
                int r = r0 + i - 10;
                if (r < HW) {
                    float mux = 0.f, muy = 0.f, exx = 0.f, eyy = 0.f, exy = 0.f;
#pragma unroll
                    for (int j = 0; j < 11; ++j) {
                        const int s = (t + 1 + j) % 11;   // compile-time
                        float w = GW(j);
                        float p = rp[s], q = rt[s];
                        float wp = w * p, wt = w * q;
                        mux += wp; muy += wt;
                        exx = fmaf(wp, p, exx);
                        eyy = fmaf(wt, q, eyy);
                        exy = fmaf(wp, q, exy);
                    }
                    mva[t & 1][x + 5] = make_float4(mux, muy, exx, eyy);
                    mvb[t & 1][x + 5] = exy;        // parity (i-10)&1 == t&1
                }
            }

            // ---- horizontal conv + SSIM for row r' = r0 + i - 11 -----------
            if (i >= 11 && i < 11 + STRIP) {        // runtime uniform
                int rr = r0 + i - 11;
                if (rr < HW) {
                    const int b = (t + 1) & 1;      // (i-11)&1, compile-time
                    float Mx = 0.f, My = 0.f, Exx = 0.f, Eyy = 0.f, Exy = 0.f;
#pragma unroll
                    for (int k = 0; k < 11; ++k) {
                        float w = GW(k);
                        float4 m4 = mva[b][x + k];
                        float  m1 = mvb[b][x + k];
                        Mx  = fmaf(w, m4.x, Mx);
                        My  = fmaf(w, m4.y, My);
                        Exx = fmaf(w, m4.z, Exx);
                        Eyy = fmaf(w, m4.w, Eyy);
                        Exy = fmaf(w, m1,  Exy);
                    }
                    float sx  = Exx - Mx * Mx;
                    float sy  = Eyy - My * My;
                    float sxy = Exy - Mx * My;
                    const float C1 = 1e-4f, C2 = 9e-4f;
                    float num = (2.f * Mx * My + C1) * (2.f * sxy + C2);
                    float den = (Mx * Mx + My * My + C1) * (sx + sy + C2);
                    acc += 0.5f * (1.f - num / (den + 1e-8f));
                }
            }

            // raw barrier: drain LDS (moment writes visible) but NOT vmcnt,
            // so depth-2 prefetch loads stay in flight across it.
            asm volatile("s_waitcnt lgkmcnt(0)" ::: "memory");
            __builtin_amdgcn_s_barrier();
        }
    }

    // ---- block reduction ---------------------------------------------------
#pragma unroll
    for (int off = 32; off > 0; off >>= 1) {
        acc   += __shfl_down(acc, off, 64);
        accl1 += __shfl_down(accl1, off, 64);
        acclw += __shfl_down(acclw, off, 64);
    }
    if ((x & 63) == 0) {
        int w = x >> 6;
        red[w] = acc; red[4 + w] = accl1; red[8 + w] = acclw;
    }
    __syncthreads();
    if (x == 0) {
        double s = 10.0 * ((double)red[0] + red[1] + red[2]  + red[3])
                 + 10.0 * ((double)red[4] + red[5] + red[6]  + red[7])
                 +  5.0 * ((double)red[8] + red[9] + red[10] + red[11]);
        atomicAdd(&ws[(blockIdx.y * NPLANE + blockIdx.x) & (NSLOT - 1)], s);
    }
}

// ---------------------------------------------------------------------------
__global__ void final_kernel(const double* __restrict__ ws, float* __restrict__ out) {
    double v = ws[threadIdx.x];
#pragma unroll
    for (int off = 32; off > 0; off >>= 1)
        v += __shfl_down(v, off, 64);
    if (threadIdx.x == 0) {
        const double denom = (double)NIMG * NCH * HW * HW;
        out[0] = (float)(v / denom);
    }
}

// ---------------------------------------------------------------------------
extern "C" void kernel_launch(void* const* d_in, const int* in_sizes, int n_in,
                              void* d_out, int out_size, void* d_ws, size_t ws_size,
                              hipStream_t stream)
{
    const float* pred   = (const float*)d_in[0];
    const float* target = (const float*)d_in[1];
    const float* lmk    = (const float*)d_in[2];
    float* out  = (float*)d_out;
    double* ws  = (double*)d_ws;

    hipLaunchKernelGGL(zero_ws_kernel, dim3(1), dim3(64), 0, stream, ws);
    hipLaunchKernelGGL(fused_kernel, dim3(NPLANE, NSTRIP), dim3(256), 0, stream,
                       pred, target, lmk, ws);
    hipLaunchKernelGGL(final_kernel, dim3(1), dim3(64), 0, stream, ws, out);
}

// Round 13
// 151.270 us; speedup vs baseline: 1.6144x; 1.0283x over previous
//
#include <hip/hip_runtime.h>
#include <cmath>

#define HW 256
#define NIMG 48
#define NCH 3
#define NPLANE (NIMG * NCH)
#define STRIP 37          // output rows per block; grid 144*7 = 1008 (r8 geometry)
#define NSTRIP 7
#define NIN (STRIP + 10)  // 47 input rows per block
#define CHUNK 22          // even multiple of 11: i%11 and i%2 compile-time
#define NCHUNK 3          // 66 slots; guards prune past i=46
#define NSLOT 64          // ws accumulator slots

typedef float f2 __attribute__((ext_vector_type(2)));
typedef float f4 __attribute__((ext_vector_type(4)));

// packed fp32 ops forced via inline asm (builtin path scalarized in r9).
// v_pk_* are per-half IEEE ops; operands are even-aligned VGPR pairs, which
// the "v" constraint on a 64-bit ext_vector provides.
#define PK_MUL(d, a, b) asm("v_pk_mul_f32 %0, %1, %2" : "=v"(d) : "v"(a), "v"(b))
#define PK_ADD_ACC(d, a) asm("v_pk_add_f32 %0, %0, %1" : "+v"(d) : "v"(a))
#define PK_FMA_ACC(d, a, b) asm("v_pk_fma_f32 %0, %1, %2, %0" : "+v"(d) : "v"(a), "v"(b))

// ws doubles: ws[0..63] partial sums of (10*d + 10*l1 + 5*lw)
__global__ void zero_ws_kernel(double* ws) {
    if (threadIdx.x < NSLOT) ws[threadIdx.x] = 0.0;
}

// ---------------------------------------------------------------------------
// Fused SSIM + L1 + weighted-L1, v-first + FORCED packed-f32 conv (round 13).
//
// Cross-round invariant (r2/r6/r7/r8/r12): per-CU throughput is constant
// across all grid/TLP/barrier configs -- dur = VALU_work / ~0.59. Only the
// numerator is attackable. This round: pk-f32 via inline asm on the two conv
// inner loops of the verified r8 kernel (78.5us):
//   v-conv/tap: pk_mul(wv) + pk_add(mu) + pk_fma(sq) + scalar fma(exy) = 4
//               vs scalar 7;  h-conv/tap: 2 pk_fma + 1 fma = 3 vs 5.
// ~25% VALU cut. pk halves are IEEE-identical per element; harness threshold
// 0.545 (r3 log) -> reassociation risk nil. r9's pk null was confounded
// (builtin scalarized + grid + threadfence) -- this isolates pk with asm.
// Geometry/structure = r8 VERBATIM (grid 1008; r12's 1296 was -4%).
// r1/r4/r5: no launch_bounds caps. r3: sbbs barrier. r10: guarded warmup.
// ---------------------------------------------------------------------------
__launch_bounds__(256)
__global__ void fused_kernel(const float* __restrict__ pred,
                             const float* __restrict__ target,
                             const float* __restrict__ lmk,
                             double* __restrict__ ws)
{
    const int plane = blockIdx.x;          // n*3 + c
    const int n     = plane / 3;
    const int r0    = blockIdx.y * STRIP;
    const int x     = threadIdx.x;

    __shared__ f4     mva[2][HW + 10];     // v-moments: mux,muy,exx,eyy
    __shared__ float  mvb[2][HW + 10];     // v-moment: exy
    __shared__ float  sxc[STRIP][24];      // crossing x per (row, edge)
    __shared__ int    srowflag[STRIP];     // bit p: poly p valid && row in y-range
    __shared__ float  slm[48];             // landmarks 36..59 (x,y)
    __shared__ float  sbbs[12];            // per poly: xmin,xmax,ymin,ymax
    __shared__ float  svalids[3];
    __shared__ float  red[12];

    // Gaussian weights as (w,w) pairs; scalar uses read the .x half (free).
    f2 gw2[6];
    {
        float gg[11]; float gs = 0.f;
#pragma unroll
        for (int q = 0; q < 11; ++q) {
            float c = (float)q - 5.0f;
            gg[q] = expf(-c * c / 4.5f);
            gs += gg[q];
        }
#pragma unroll
        for (int q = 0; q < 6; ++q) { float w = gg[q] / gs; gw2[q] = (f2){w, w}; }
    }
#define GW2(j) gw2[(j) < 6 ? (j) : 10 - (j)]   // j always compile-time
#define GW(j)  (GW2(j).x)

    // ---- prologue ----------------------------------------------------------
    if (x < 48) slm[x] = lmk[n * 136 + 72 + x];
    if (x < 5) {
        const f4 z4 = {0.f, 0.f, 0.f, 0.f};
        mva[0][x] = z4; mva[0][261 + x] = z4;
        mva[1][x] = z4; mva[1][261 + x] = z4;
        mvb[0][x] = 0.f; mvb[0][261 + x] = 0.f;
        mvb[1][x] = 0.f; mvb[1][261 + x] = 0.f;
    }
    __syncthreads();   // slm ready

    if (x < 3) {
        const int s0 = (x == 0) ? 0 : (x == 1) ? 6 : 12;
        const int L  = (x == 2) ? 12 : 6;
        float xmn = 3e38f, xmx = -3e38f, ymn = 3e38f, ymx = -3e38f;
        for (int q = 0; q < L; ++q) {
            float px = slm[2 * (s0 + q)], py = slm[2 * (s0 + q) + 1];
            xmn = fminf(xmn, px); xmx = fmaxf(xmx, px);
            ymn = fminf(ymn, py); ymx = fmaxf(ymx, py);
        }
        xmn = floorf(xmn); xmx = floorf(xmx); ymn = floorf(ymn); ymx = floorf(ymx);
        sbbs[4 * x + 0] = xmn; sbbs[4 * x + 1] = xmx;
        sbbs[4 * x + 2] = ymn; sbbs[4 * x + 3] = ymx;
        svalids[x] = (xmn >= 0.f && ymn >= 0.f && xmx < 256.f && ymx < 256.f) ? 1.f : 0.f;
    }

#pragma unroll
    for (int u = 0; u < (STRIP * 24 + 255) / 256; ++u) {
        int idx = x + 256 * u;
        if (idx < STRIP * 24) {
            int r = idx / 24, e = idx - r * 24;
            float Y = (float)(r0 + r);
            const int s0 = (e < 6) ? 0 : (e < 12) ? 6 : 12;
            const int L  = (e < 12) ? 6 : 12;
            int il = e - s0;
            int i2 = (il + 1 == L) ? 0 : il + 1;
            float x1 = slm[2 * (s0 + il)], y1 = slm[2 * (s0 + il) + 1];
            float x2 = slm[2 * (s0 + i2)], y2 = slm[2 * (s0 + i2) + 1];
            bool crossing = (y1 > Y) != (y2 > Y);
            // exact reference fp32 expression order
            float xc = (x2 - x1) * (Y - y1) / (y2 - y1 + 1e-6f) + x1;
            sxc[r][e] = crossing ? xc : -3e38f;
        }
    }
    __syncthreads();   // sbbs/svalids visible to all (round-3 fix); sxc ready

    if (x < STRIP) {
        float Y = (float)(r0 + x);
        int f = 0;
        if (svalids[0] != 0.f && Y >= sbbs[2]  && Y < sbbs[3])  f |= 1;
        if (svalids[1] != 0.f && Y >= sbbs[6]  && Y < sbbs[7])  f |= 2;
        if (svalids[2] != 0.f && Y >= sbbs[10] && Y < sbbs[11]) f |= 4;
        srowflag[x] = f;
    }
    __syncthreads();   // srowflag ready; pads ready

    // column-x base pointers (coalesced across threads)
    const float* __restrict__ pp = pred   + (size_t)plane * (HW * HW) + x;
    const float* __restrict__ tp = target + (size_t)plane * (HW * HW) + x;

    // raw-row register ring: 11 x (p,t) pairs (22 VGPR) + depth-2 prefetch
    f2 ring[11];
    float pfap, pfat, pfbp, pfbt;
    {   // warmup: rows i=0 (r0-5) and i=1 (r0-4); GUARDED ternaries (r10 fix)
        int ra = r0 - 5;
        bool va = (ra >= 0);
        pfap = va ? pp[(size_t)ra * HW] : 0.f;
        pfat = va ? tp[(size_t)ra * HW] : 0.f;
        int rb = r0 - 4;
        bool vb = (rb >= 0);
        pfbp = vb ? pp[(size_t)rb * HW] : 0.f;
        pfbt = vb ? tp[(size_t)rb * HW] : 0.f;
    }

    float acc = 0.f, accl1 = 0.f, acclw = 0.f;
    const float X = (float)x;

    for (int c = 0; c < NCHUNK; ++c) {
#pragma unroll
        for (int t = 0; t < CHUNK; ++t) {
            const int i  = CHUNK * c + t;   // runtime (c), t compile-time
            if (i >= NIN) continue;         // uniform; prunes chunk-2 tail
            const int sr = t % 11;          // ring slot of row i (22c % 11 == 0)

            {
                // consume prefetch (issued 2 iters ago) into the ring
                if ((t & 1) == 0) ring[sr] = (f2){pfap, pfat};
                else              ring[sr] = (f2){pfbp, pfbt};
                // issue load for row i+2 (waited at use, 2 iters later)
                {
                    int rin2 = r0 - 3 + i;
                    bool v = (i + 2 < NIN) && (rin2 >= 0) && (rin2 < HW);
                    float lp = 0.f, lt = 0.f;
                    if (v) {
                        lp = pp[(size_t)rin2 * HW];
                        lt = tp[(size_t)rin2 * HW];
                    }
                    if ((t & 1) == 0) { pfap = lp; pfat = lt; }
                    else              { pfbp = lp; pfbt = lt; }
                }

                // ---- L1 + weighted L1 for raw row r_in = r0-5+i ------------
                if (i >= 5 && i < 5 + STRIP) {      // runtime uniform
                    int r_in = r0 - 5 + i;
                    if (r_in < HW) {
                        f2 pr = ring[sr];
                        float ad = fabsf(pr.x - pr.y);
                        accl1 += ad;
                        float wgt = 1.f;
                        const int flags = srowflag[i - 5];   // broadcast read
                        if (flags) {                 // wave-uniform branch
                            const float* xc = sxc[i - 5];
                            int c0 = 0, c1 = 0, c2 = 0;
#pragma unroll
                            for (int e = 0; e < 6; ++e)   c0 += (X < xc[e]) ? 1 : 0;
#pragma unroll
                            for (int e = 6; e < 12; ++e)  c1 += (X < xc[e]) ? 1 : 0;
#pragma unroll
                            for (int e = 12; e < 24; ++e) c2 += (X < xc[e]) ? 1 : 0;
                            if ((flags & 1) && (c0 & 1) && X >= sbbs[0] && X < sbbs[1]) wgt += 3.f;
                            if ((flags & 2) && (c1 & 1) && X >= sbbs[4] && X < sbbs[5]) wgt += 3.f;
                            if ((flags & 4) && (c2 & 1) && X >= sbbs[8] && X < sbbs[9]) wgt += 2.f;
                        }
                        acclw += wgt * ad;
                    }
                }
            }

            // ---- vertical conv (pk) -> moment row r = r0 + i - 10 ----------
            if (i >= 10) {                          // i < 10+STRIP always here
                int r = r0 + i - 10;
                if (r < HW) {
                    f2 mu = {0.f, 0.f};             // (mux, muy)
                    f2 sq = {0.f, 0.f};             // (exx, eyy)
                    float exy = 0.f;
#pragma unroll
                    for (int j = 0; j < 11; ++j) {
                        const int s = (t + 1 + j) % 11;   // compile-time
                        f2 w2 = GW2(j);
                        f2 v  = ring[s];
                        f2 wv;
                        PK_MUL(wv, w2, v);          // (w*p, w*t)
                        PK_ADD_ACC(mu, wv);         // mu += wv
                        PK_FMA_ACC(sq, wv, v);      // sq += wv*v
                        exy = fmaf(wv.x, v.y, exy); // scalar
                    }
                    mva[t & 1][x + 5] = (f4){mu.x, mu.y, sq.x, sq.y};
                    mvb[t & 1][x + 5] = exy;        // parity (i-10)&1 == t&1
                }
            }

            // ---- horizontal conv (pk) + SSIM for row r' = r0 + i - 11 ------
            if (i >= 11) {                          // i < 11+STRIP always here
                int rr = r0 + i - 11;
                if (rr < HW) {
                    const int b = (t + 1) & 1;      // (i-11)&1, compile-time
                    f2 M = {0.f, 0.f};              // (Mx, My)
                    f2 E = {0.f, 0.f};              // (Exx, Eyy)
                    float Exy = 0.f;
#pragma unroll
                    for (int k = 0; k < 11; ++k) {
                        f2 w2 = GW2(k);
                        f4 m4 = mva[b][x + k];
                        f2 lo = __builtin_shufflevector(m4, m4, 0, 1);
                        f2 hi = __builtin_shufflevector(m4, m4, 2, 3);
                        float m1 = mvb[b][x + k];
                        PK_FMA_ACC(M, w2, lo);
                        PK_FMA_ACC(E, w2, hi);
                        Exy = fmaf(w2.x, m1, Exy);
                    }
                    float sx  = E.x - M.x * M.x;
                    float sy  = E.y - M.y * M.y;
                    float sxy = Exy - M.x * M.y;
                    const float C1 = 1e-4f, C2 = 9e-4f;
                    float num = (2.f * M.x * M.y + C1) * (2.f * sxy + C2);
                    float den = (M.x * M.x + M.y * M.y + C1) * (sx + sy + C2);
                    acc += 0.5f * (1.f - num / (den + 1e-8f));
                }
            }

            // raw barrier: drain LDS (moment writes visible) but NOT vmcnt,
            // so depth-2 prefetch loads stay in flight across it.
            asm volatile("s_waitcnt lgkmcnt(0)" ::: "memory");
            __builtin_amdgcn_s_barrier();
        }
    }

    // ---- block reduction ---------------------------------------------------
#pragma unroll
    for (int off = 32; off > 0; off >>= 1) {
        acc   += __shfl_down(acc, off, 64);
        accl1 += __shfl_down(accl1, off, 64);
        acclw += __shfl_down(acclw, off, 64);
    }
    if ((x & 63) == 0) {
        int w = x >> 6;
        red[w] = acc; red[4 + w] = accl1; red[8 + w] = acclw;
    }
    __syncthreads();
    if (x == 0) {
        double s = 10.0 * ((double)red[0] + red[1] + red[2]  + red[3])
                 + 10.0 * ((double)red[4] + red[5] + red[6]  + red[7])
                 +  5.0 * ((double)red[8] + red[9] + red[10] + red[11]);
        atomicAdd(&ws[(blockIdx.y * NPLANE + blockIdx.x) & (NSLOT - 1)], s);
    }
}

// ---------------------------------------------------------------------------
__global__ void final_kernel(const double* __restrict__ ws, float* __restrict__ out) {
    double v = ws[threadIdx.x];
#pragma unroll
    for (int off = 32; off > 0; off >>= 1)
        v += __shfl_down(v, off, 64);
    if (threadIdx.x == 0) {
        const double denom = (double)NIMG * NCH * HW * HW;
        out[0] = (float)(v / denom);
    }
}

// ---------------------------------------------------------------------------
extern "C" void kernel_launch(void* const* d_in, const int* in_sizes, int n_in,
                              void* d_out, int out_size, void* d_ws, size_t ws_size,
                              hipStream_t stream)
{
    const float* pred   = (const float*)d_in[0];
    const float* target = (const float*)d_in[1];
    const float* lmk    = (const float*)d_in[2];
    float* out  = (float*)d_out;
    double* ws  = (double*)d_ws;

    hipLaunchKernelGGL(zero_ws_kernel, dim3(1), dim3(64), 0, stream, ws);
    hipLaunchKernelGGL(fused_kernel, dim3(NPLANE, NSTRIP), dim3(256), 0, stream,
                       pred, target, lmk, ws);
    hipLaunchKernelGGL(final_kernel, dim3(1), dim3(64), 0, stream, ws, out);
}